// Round 11
// baseline (97.331 us; speedup 1.0000x reference)
//
#include <hip/hip_runtime.h>
#include <hip/hip_bf16.h>

typedef __bf16 bf16;
typedef __attribute__((ext_vector_type(8))) __bf16 bf16x8;
typedef __attribute__((ext_vector_type(4))) float f32x4;
typedef __attribute__((ext_vector_type(16))) float f32x16;

#define BB   4
#define NN   2048
#define DD   512
#define HH   8
#define DHH  64
#define TT   (BB*NN)     // 8192
#define NUU  (HH*4*DHH)  // 2048

#define AS1 __attribute__((address_space(1)))
#define AS3 __attribute__((address_space(3)))
// async global->LDS, 16B per lane; LDS dest = wave-uniform base + lane*16 (linear)
__device__ __forceinline__ void gload16(const void* g, void* l){
  __builtin_amdgcn_global_load_lds((const AS1 void*)g, (AS3 void*)l, 16, 0, 0);
}

// fast silu: v_rcp_f32 (1 ulp) instead of precise f32 divide (~8 instrs)
__device__ __forceinline__ float silu_fast(float x){
  return x * __builtin_amdgcn_rcpf(1.0f + __expf(-x));
}

// pack two f32 -> one u32 of 2 bf16
__device__ __forceinline__ unsigned pk2(float a, float b){
  return (unsigned)__builtin_bit_cast(unsigned short, (bf16)a)
       | ((unsigned)__builtin_bit_cast(unsigned short, (bf16)b) << 16);
}

// xor-32 lane exchange: a' = [a_lo | b_lo], b' = [a_hi | b_hi]
__device__ __forceinline__ void plswap(unsigned &a, unsigned &b){
  asm volatile("v_permlane32_swap_b32 %0, %1" : "+v"(a), "+v"(b));
}

// ---- k_attn work table: 24 entries per (b,h) group, qt|j0<<4|cnt<<10 ----
// qt<8: one chunk [0, 2qt+1]; qt>=8: two chunks [0,qt] and [qt+1, 2qt+1].
// Ranks arranged so ranks {k, 8+k, 16+k} (the 3 blocks landing on one CU)
// sum to exactly 34 tiles for every k.  (round-4/6 verified: 40.9us)
__constant__ unsigned ATBL[24] = {
  7u|(0u<<4)|(16u<<10), 15u|(0u<<4)|(16u<<10), 14u|(0u<<4)|(15u<<10), 14u|(15u<<4)|(15u<<10),
  6u|(0u<<4)|(14u<<10), 13u|(0u<<4)|(14u<<10), 12u|(0u<<4)|(13u<<10), 11u|(0u<<4)|(12u<<10),
  15u|(16u<<4)|(16u<<10), 13u|(14u<<4)|(14u<<10), 12u|(13u<<4)|(13u<<10), 10u|(0u<<4)|(11u<<10),
  10u|(11u<<4)|(11u<<10), 9u|(0u<<4)|(10u<<10), 5u|(0u<<4)|(12u<<10), 11u|(12u<<4)|(12u<<10),
  0u|(0u<<4)|(2u<<10), 1u|(0u<<4)|(4u<<10), 2u|(0u<<4)|(6u<<10), 3u|(0u<<4)|(8u<<10),
  8u|(0u<<4)|(9u<<10), 9u|(10u<<4)|(10u<<10), 8u|(9u<<4)|(9u<<10), 4u|(0u<<4)|(10u<<10)
};

// ---------- fused pre-pass: weight transposes + input LayerNorm ----------
// blocks [0,1280): transpose+cast (bx2<64 -> w_uvqk 512x2048, else w_proj 512x512)
// blocks [1280,3328): LayerNorm over 512 + cast, 4 rows/block
__global__ void k_pre(const float* __restrict__ w1, bf16* __restrict__ o1,
                      const float* __restrict__ w2, bf16* __restrict__ o2,
                      const float* __restrict__ x, const float* __restrict__ g,
                      const float* __restrict__ bta, bf16* __restrict__ xn){
  int bx = blockIdx.x;
  int t  = threadIdx.x;
  if (bx < 1280){
    __shared__ float tile[32][33];
    int tx = t & 31, ty = t >> 5;
    int bx2 = bx % 80, by = bx / 80;
    const float* in; bf16* out; int R, C, c0;
    if (bx2 < 64){ in = w1; out = o1; R = 512; C = 2048; c0 = bx2*32; }
    else         { in = w2; out = o2; R = 512; C = 512;  c0 = (bx2-64)*32; }
    int r0 = by*32;
    #pragma unroll
    for (int i=0;i<4;i++) tile[ty+i*8][tx] = in[(size_t)(r0+ty+i*8)*C + c0+tx];
    __syncthreads();
    #pragma unroll
    for (int i=0;i<4;i++) out[(size_t)(c0+ty+i*8)*R + r0+tx] = (bf16)tile[tx][ty+i*8];
  } else {
    int lane = t & 63;
    int row  = (bx-1280)*4 + (t>>6);
    const float* xr = x + (size_t)row*512 + lane*8;
    float4 v0 = *(const float4*)xr;
    float4 v1 = *(const float4*)(xr+4);
    float vv[8] = {v0.x,v0.y,v0.z,v0.w,v1.x,v1.y,v1.z,v1.w};
    float s = 0.f, ss = 0.f;
    #pragma unroll
    for (int j=0;j<8;j++){ s += vv[j]; ss += vv[j]*vv[j]; }
    #pragma unroll
    for (int d=32; d; d>>=1){ s += __shfl_xor(s,d); ss += __shfl_xor(ss,d); }
    float m  = s * (1.f/512.f);
    float vr = ss * (1.f/512.f) - m*m;
    float rs = rsqrtf(vr + 1e-5f);
    const float* gp = g + lane*8;
    const float* bp = bta + lane*8;
    bf16x8 o;
    #pragma unroll
    for (int j=0;j<8;j++) o[j] = (bf16)((vv[j]-m)*rs*gp[j] + bp[j]);
    *(bf16x8*)(xn + (size_t)row*512 + lane*8) = o;
  }
}

// ---------- LayerNorm(attn0[+attn1]) * user gate -> bf16 ----------
__global__ void k_ln_gate(const float* __restrict__ attn0, const float* __restrict__ attn1,
                          const float* __restrict__ g, const float* __restrict__ bta,
                          const bf16* __restrict__ uvqk, bf16* __restrict__ out){
  int lane = threadIdx.x & 63;
  int row  = blockIdx.x*4 + (threadIdx.x>>6);
  const float* xr = attn0 + (size_t)row*512 + lane*8;
  float4 v0 = *(const float4*)xr;
  float4 v1 = *(const float4*)(xr+4);
  float vv[8] = {v0.x,v0.y,v0.z,v0.w,v1.x,v1.y,v1.z,v1.w};
  if (((row & (NN-1)) >> 7) >= 8){            // q-tile had 2 kv-chunks: sum partials
    const float* x2 = attn1 + (size_t)row*512 + lane*8;
    float4 w0 = *(const float4*)x2;
    float4 w1 = *(const float4*)(x2+4);
    vv[0]+=w0.x; vv[1]+=w0.y; vv[2]+=w0.z; vv[3]+=w0.w;
    vv[4]+=w1.x; vv[5]+=w1.y; vv[6]+=w1.z; vv[7]+=w1.w;
  }
  float s = 0.f, ss = 0.f;
  #pragma unroll
  for (int j=0;j<8;j++){ s += vv[j]; ss += vv[j]*vv[j]; }
  #pragma unroll
  for (int d=32; d; d>>=1){ s += __shfl_xor(s,d); ss += __shfl_xor(ss,d); }
  float m  = s * (1.f/512.f);
  float vr = ss * (1.f/512.f) - m*m;
  float rs = rsqrtf(vr + 1e-5f);
  const float* gp = g + lane*8;
  const float* bp = bta + lane*8;
  const bf16* up = uvqk + (size_t)row*NUU + (lane>>3)*256 + ((lane*8)&63);
  bf16x8 uu = *(const bf16x8*)up;
  bf16x8 o;
  #pragma unroll
  for (int j=0;j<8;j++)
    o[j] = (bf16)(((vv[j]-m)*rs*gp[j] + bp[j]) * (float)uu[j]);
  *(bf16x8*)(out + (size_t)row*512 + lane*8) = o;
}

// ---------- 128x128 bf16 MFMA GEMM, K=512, BK=64, 4 waves (2x2) ----------
// 1-D grid with XCD-chunked swizzle (gridDim.x % 8 == 0 required).
// EPI==0 additionally writes the V-slice transposed into vtout (fused k_vt):
// tiles with n0%256==0 have wc==1 covering cols [n0+64, n0+128) = V of head n0>>8.
// The V-slice is NOT stored into Cout (nothing reads it there) -> -8MB writes.
// (round-8 verified orientation; operand-swap variant regressed in round 9)
template<int EPI>
__global__ __launch_bounds__(256) void k_gemm(const bf16* __restrict__ A,
                                              const bf16* __restrict__ BT,
                                              int Nd, const float* __restrict__ resid,
                                              void* __restrict__ Cout,
                                              bf16* __restrict__ vtout){
  __shared__ __align__(16) char smem[32768];
  char* As = smem;
  char* Bs = smem + 16384;
  const int K = 512;
  int t = threadIdx.x, lane = t & 63, wid = t >> 6;
  int wr = wid >> 1, wc = wid & 1;
  int lin = blockIdx.x;
  int wk  = (lin & 7)*((int)gridDim.x >> 3) + (lin >> 3);   // XCD-chunked
  int nx  = Nd >> 7;
  int m0 = (wk / nx) * 128, n0 = (wk % nx) * 128;
  int blk = (lane & 7) ^ (lane >> 3);           // swizzled 16B-slot within row
  const bf16* gA = A  + (size_t)(m0 + wid*32 + (lane>>3))*K + blk*8;
  const bf16* gB = BT + (size_t)(n0 + wid*32 + (lane>>3))*K + blk*8;
  f32x4 acc[4][4] = {};
  for (int k0 = 0; k0 < K; k0 += 64){
    __syncthreads();
    #pragma unroll
    for (int c = 0; c < 4; ++c){
      gload16(gA + (size_t)c*8*K, As + wid*4096 + c*1024);
      gload16(gB + (size_t)c*8*K, Bs + wid*4096 + c*1024);
    }
    gA += 64; gB += 64;
    __syncthreads();
    #pragma unroll
    for (int kk = 0; kk < 64; kk += 32){
      int c0 = kk + (lane >> 4) * 8;
      bf16x8 a[4], b[4];
      #pragma unroll
      for (int i = 0; i < 4; i++){
        int ra = wr*64 + i*16 + (lane & 15);
        a[i] = *(const bf16x8*)(As + (((ra*64 + c0)*2) ^ ((ra & 7) << 4)));
        int rb = wc*64 + i*16 + (lane & 15);
        b[i] = *(const bf16x8*)(Bs + (((rb*64 + c0)*2) ^ ((rb & 7) << 4)));
      }
      #pragma unroll
      for (int i = 0; i < 4; i++)
        #pragma unroll
        for (int jj = 0; jj < 4; jj++)
          acc[i][jj] = __builtin_amdgcn_mfma_f32_16x16x32_bf16(a[i], b[jj], acc[i][jj], 0, 0, 0);
    }
  }
  bool isv = (EPI == 0) && ((n0 & 255) == 0) && (wc == 1);
  #pragma unroll
  for (int i = 0; i < 4; i++){
    #pragma unroll
    for (int jj = 0; jj < 4; jj++){
      int col = n0 + wc*64 + jj*16 + (lane & 15);
      if (EPI == 0){
        union { unsigned long long u; ushort s[4]; } pw;
        #pragma unroll
        for (int r = 0; r < 4; r++){
          int rowg = m0 + wr*64 + i*16 + (lane >> 4)*4 + r;
          float sv = silu_fast(acc[i][jj][r]);
          if (!isv) ((bf16*)Cout)[(size_t)rowg*Nd + col] = (bf16)sv;
          pw.s[r] = __builtin_bit_cast(ushort, (bf16)sv);
        }
        if (isv){
          int dh    = jj*16 + (lane & 15);
          int rowg0 = m0 + wr*64 + i*16 + (lane >> 4)*4;
          int bb = rowg0 >> 11, nn = rowg0 & (NN-1);
          int hh = n0 >> 8;
          *(unsigned long long*)(vtout + ((size_t)((bb*HH + hh)*64 + dh)*NN + nn)) = pw.u;
        }
      } else {
        #pragma unroll
        for (int r = 0; r < 4; r++){
          int rowg = m0 + wr*64 + i*16 + (lane >> 4)*4 + r;
          ((float*)Cout)[(size_t)rowg*Nd + col] = acc[i][jj][r] + resid[(size_t)rowg*Nd + col];
        }
      }
    }
  }
}

// ---------- HSTU attention v11: paired sub-tiles (intra-wave ILP x2) ----------
// Round-10 structure (single barrier/tile, plain stores, setprio) with the two
// 32-kv sub-tiles computed as {QK0,QK1} -> {silu0,silu1} -> {PV0,PV1} in
// separate registers: 2 independent MFMA chains + 32 independent exp/rcp
// chains for the scheduler to overlap (the latency-chain fix occupancy
// couldn't provide). Same math, same guards, same stores.
__global__ __launch_bounds__(256, 4) void k_attn(const bf16* __restrict__ uv,
                                                 const bf16* __restrict__ vt,
                                                 float* __restrict__ attn0,
                                                 float* __restrict__ attn1,
                                                 const int* __restrict__ scal){
  __shared__ __align__(16) char smem[32768];
  // buf c (c=0,1): K[64][64] at smem+c*16384, V^T[64][64] at +8192
  int t = threadIdx.x, lane = t & 63, w = t >> 6;     // w = 0..3
  int hi5 = lane >> 5;
  int l31 = lane & 31;
  int lin = blockIdx.x;                       // 0..767 hardware dispatch order
  int pos = lin & 255;                        // ~CU slot (XCD round-robin)
  int grp = pos & 31;                         // (b,h): 4 groups per XCD per slot
  int rank = (lin >> 8)*8 + (pos >> 5);       // 0..23
  unsigned e = ATBL[rank];
  int qt = e & 15;
  int j0 = (int)((e >> 4) & 63);
  int j1 = j0 + (int)(e >> 10) - 1;
  float* ob = j0 ? attn1 : attn0;             // j0>0 <=> second chunk of a pair
  int b = grp >> 3, h = grp & 7;
  int tok0 = b*NN + qt*128;
  float sinv = 1.0f / (float)(scal[0]);       // = 2^-11 exact; applied at epilogue

  int blk  = (lane & 7) ^ (lane >> 3);      // pre-swizzled 16B slot within 128B row
  int rsub = lane >> 3;                     // row-within-8

  // ---- Q fragments straight from global (32B row segments, L2/L3-resident) ----
  bf16x8 qfrag[4];
  {
    const bf16* gq = uv + (size_t)(tok0 + w*32 + l31)*NUU + h*256 + 128 + hi5*8;
    #pragma unroll
    for (int ks = 0; ks < 4; ++ks)
      qfrag[ks] = *(const bf16x8*)(gq + ks*16);
  }
  // ---- prologue: stage K/V(j0) into buf0 (4 DMA loads per wave) ----
  const bf16* gk = uv + (size_t)(b*NN + j0*64 + w*16 + rsub)*NUU + h*256 + 192 + blk*8;
  const bf16* gv = vt + (size_t)((b*HH + h)*64 + w*16 + rsub)*NN + j0*64 + blk*8;
  gload16(gk,                  smem + w*2048);
  gload16(gk + (size_t)8*NUU,  smem + w*2048 + 1024);
  gload16(gv,                  smem + 8192 + w*2048);
  gload16(gv + (size_t)8*NN,   smem + 8192 + w*2048 + 1024);
  gk += (size_t)64*NUU; gv += 64;

  f32x16 oacc[2] = {};
  int qmin  = qt*128 + w*32;                 // this wave's lowest q row (global)
  int qglob = qmin + l31;                    // lane's q row (global)
  int cur = 0;
  union PU { unsigned u[8]; bf16x8 v[2]; };
  for (int j = j0; j <= j1; ++j){
    // wait for buf[cur]'s staging (issued last iteration; had the whole
    // previous compute phase to land), then the single barrier: buf[cur]
    // complete for all waves AND all waves done reading buf[cur^1]
    asm volatile("s_waitcnt vmcnt(0)" ::: "memory");
    __builtin_amdgcn_s_barrier();
    if (j < j1){                             // prefetch(j+1) into the free buffer
      char* nb = smem + (cur^1)*16384;
      gload16(gk,                 nb + w*2048);
      gload16(gk + (size_t)8*NUU, nb + w*2048 + 1024);
      gload16(gv,                 nb + 8192 + w*2048);
      gload16(gv + (size_t)8*NN,  nb + 8192 + w*2048 + 1024);
      gk += (size_t)64*NUU; gv += 64;
    }
    const char* Ks = smem + cur*16384;
    const char* Vs = Ks + 8192;
    int kv0 = j*64, kv1 = j*64 + 32;
    bool d0 = (kv0 < qmin + 32);             // wave-uniform guards
    bool d1 = (kv1 < qmin + 32);
    // ---- QK^T for BOTH sub-tiles (independent MFMA chains) ----
    f32x16 s0 = {}, s1 = {};
    __builtin_amdgcn_s_setprio(1);
    if (d0){
      int rk = l31;
      #pragma unroll
      for (int ks = 0; ks < 4; ++ks){
        int c0 = ks*16 + hi5*8;
        bf16x8 ak = *(const bf16x8*)(Ks + (((rk*64 + c0)*2) ^ ((rk & 7) << 4)));
        s0 = __builtin_amdgcn_mfma_f32_32x32x16_bf16(ak, qfrag[ks], s0, 0, 0, 0);
      }
    }
    if (d1){
      int rk = 32 + l31;
      #pragma unroll
      for (int ks = 0; ks < 4; ++ks){
        int c0 = ks*16 + hi5*8;
        bf16x8 ak = *(const bf16x8*)(Ks + (((rk*64 + c0)*2) ^ ((rk & 7) << 4)));
        s1 = __builtin_amdgcn_mfma_f32_32x32x16_bf16(ak, qfrag[ks], s1, 0, 0, 0);
      }
    }
    __builtin_amdgcn_s_setprio(0);
    // ---- silu + pack for BOTH sub-tiles (32 independent trans chains) ----
    PU P0, P1;
    if (d0){
      if (kv0 + 31 <= qmin){
        #pragma unroll
        for (int m = 0; m < 4; ++m){
          P0.u[2*m]   = pk2(silu_fast(s0[4*m+0]), silu_fast(s0[4*m+1]));
          P0.u[2*m+1] = pk2(silu_fast(s0[4*m+2]), silu_fast(s0[4*m+3]));
        }
      } else {
        #pragma unroll
        for (int m = 0; m < 4; ++m){
          float pr[4];
          #pragma unroll
          for (int r = 0; r < 4; ++r){
            int kvg = kv0 + 8*m + 4*hi5 + r;
            pr[r] = (kvg <= qglob) ? silu_fast(s0[4*m+r]) : 0.0f;
          }
          P0.u[2*m]   = pk2(pr[0], pr[1]);
          P0.u[2*m+1] = pk2(pr[2], pr[3]);
        }
      }
      plswap(P0.u[0], P0.u[2]); plswap(P0.u[1], P0.u[3]);
      plswap(P0.u[4], P0.u[6]); plswap(P0.u[5], P0.u[7]);
    }
    if (d1){
      if (kv1 + 31 <= qmin){
        #pragma unroll
        for (int m = 0; m < 4; ++m){
          P1.u[2*m]   = pk2(silu_fast(s1[4*m+0]), silu_fast(s1[4*m+1]));
          P1.u[2*m+1] = pk2(silu_fast(s1[4*m+2]), silu_fast(s1[4*m+3]));
        }
      } else {
        #pragma unroll
        for (int m = 0; m < 4; ++m){
          float pr[4];
          #pragma unroll
          for (int r = 0; r < 4; ++r){
            int kvg = kv1 + 8*m + 4*hi5 + r;
            pr[r] = (kvg <= qglob) ? silu_fast(s1[4*m+r]) : 0.0f;
          }
          P1.u[2*m]   = pk2(pr[0], pr[1]);
          P1.u[2*m+1] = pk2(pr[2], pr[3]);
        }
      }
      plswap(P1.u[0], P1.u[2]); plswap(P1.u[1], P1.u[3]);
      plswap(P1.u[4], P1.u[6]); plswap(P1.u[5], P1.u[7]);
    }
    // ---- PV for BOTH sub-tiles ----
    __builtin_amdgcn_s_setprio(1);
    if (d0){
      #pragma unroll
      for (int kh = 0; kh < 2; ++kh){
        int c0 = kh*16 + hi5*8;
        #pragma unroll
        for (int dsb = 0; dsb < 2; ++dsb){
          int rv = dsb*32 + l31;
          bf16x8 vb = *(const bf16x8*)(Vs + (((rv*64 + c0)*2) ^ ((rv & 7) << 4)));
          oacc[dsb] = __builtin_amdgcn_mfma_f32_32x32x16_bf16(P0.v[kh], vb, oacc[dsb], 0, 0, 0);
        }
      }
    }
    if (d1){
      #pragma unroll
      for (int kh = 0; kh < 2; ++kh){
        int c0 = 32 + kh*16 + hi5*8;
        #pragma unroll
        for (int dsb = 0; dsb < 2; ++dsb){
          int rv = dsb*32 + l31;
          bf16x8 vb = *(const bf16x8*)(Vs + (((rv*64 + c0)*2) ^ ((rv & 7) << 4)));
          oacc[dsb] = __builtin_amdgcn_mfma_f32_32x32x16_bf16(P1.v[kh], vb, oacc[dsb], 0, 0, 0);
        }
      }
    }
    __builtin_amdgcn_s_setprio(0);
    cur ^= 1;
  }
  // oacc[dsb] reg r = O[q = (r&3)+4*hi5+8*(r>>2)][dh = dsb*32 + l31]
  // plain coalesced stores into this chunk's partial buffer
  #pragma unroll
  for (int dsb = 0; dsb < 2; ++dsb){
    #pragma unroll
    for (int r = 0; r < 16; ++r){
      int qrow = (r & 3) + 4*hi5 + 8*(r >> 2);
      ob[(size_t)(tok0 + w*32 + qrow)*DD + h*64 + dsb*32 + l31] = oacc[dsb][r] * sinv;
    }
  }
}

extern "C" void kernel_launch(void* const* d_in, const int* in_sizes, int n_in,
                              void* d_out, int out_size, void* d_ws, size_t ws_size,
                              hipStream_t stream){
  (void)in_sizes; (void)n_in; (void)out_size; (void)ws_size;
  const float* x      = (const float*)d_in[0];
  const float* ln1_g  = (const float*)d_in[1];
  const float* ln1_b  = (const float*)d_in[2];
  const float* w_uvqk = (const float*)d_in[3];
  const float* ln2_g  = (const float*)d_in[4];
  const float* ln2_b  = (const float*)d_in[5];
  const float* w_proj = (const float*)d_in[6];
  const int*   scal   = (const int*)d_in[7];
  float* out = (float*)d_out;

  char* ws = (char*)d_ws;
  bf16*  wT1  = (bf16*)(ws);                          // 2 MB   [2048][512]
  bf16*  wT2  = (bf16*)(ws + (2u<<20));               // 0.5 MB [512][512]
  bf16*  xn   = (bf16*)(ws + (2u<<20) + (512u<<10));  // 8 MB   [8192][512] (reused as gated)
  bf16*  uvq  = (bf16*)(ws + (10u<<20) + (512u<<10)); // 32 MB  [8192][2048]
  float* attn0= (float*)(ws + (42u<<20) + (512u<<10));// 16 MB  [8192][512] f32 (chunk 0)
  bf16*  vtb  = (bf16*)(ws + (58u<<20) + (512u<<10)); // 8 MB   [4][8][64][2048]
  float* attn1= (float*)(ws + (66u<<20) + (512u<<10));// 16 MB  [8192][512] f32 (chunk 1)

  k_pre<<<dim3(3328), dim3(256), 0, stream>>>(w_uvqk, wT1, w_proj, wT2,
                                              x, ln1_g, ln1_b, xn);
  k_gemm<0><<<dim3(1024), dim3(256), 0, stream>>>(xn, wT1, 2048, nullptr, (void*)uvq, vtb);
  k_attn<<<dim3(768), dim3(256), 0, stream>>>(uvq, vtb, attn0, attn1, scal);
  k_ln_gate<<<TT/4, 256, 0, stream>>>(attn0, attn1, ln2_g, ln2_b, uvq, xn);
  k_gemm<1><<<dim3(256), dim3(256), 0, stream>>>(xn, wT2, 512, x, (void*)out, nullptr);
}

// Round 12
// 94.749 us; speedup vs baseline: 1.0272x; 1.0272x over previous
//
#include <hip/hip_runtime.h>
#include <hip/hip_bf16.h>

typedef __bf16 bf16;
typedef __attribute__((ext_vector_type(8))) __bf16 bf16x8;
typedef __attribute__((ext_vector_type(4))) float f32x4;
typedef __attribute__((ext_vector_type(16))) float f32x16;

#define BB   4
#define NN   2048
#define DD   512
#define HH   8
#define DHH  64
#define TT   (BB*NN)     // 8192
#define NUU  (HH*4*DHH)  // 2048

#define AS1 __attribute__((address_space(1)))
#define AS3 __attribute__((address_space(3)))
// async global->LDS, 16B per lane; LDS dest = wave-uniform base + lane*16 (linear)
__device__ __forceinline__ void gload16(const void* g, void* l){
  __builtin_amdgcn_global_load_lds((const AS1 void*)g, (AS3 void*)l, 16, 0, 0);
}

// fast silu: v_rcp_f32 (1 ulp) instead of precise f32 divide (~8 instrs)
__device__ __forceinline__ float silu_fast(float x){
  return x * __builtin_amdgcn_rcpf(1.0f + __expf(-x));
}

// pack two f32 -> one u32 of 2 bf16
__device__ __forceinline__ unsigned pk2(float a, float b){
  return (unsigned)__builtin_bit_cast(unsigned short, (bf16)a)
       | ((unsigned)__builtin_bit_cast(unsigned short, (bf16)b) << 16);
}

// xor-32 lane exchange: a' = [a_lo | b_lo], b' = [a_hi | b_hi]
__device__ __forceinline__ void plswap(unsigned &a, unsigned &b){
  asm volatile("v_permlane32_swap_b32 %0, %1" : "+v"(a), "+v"(b));
}

// ---- k_attn work table: 24 entries per (b,h) group, qt|j0<<4|cnt<<10 ----
// qt<8: one chunk [0, 2qt+1]; qt>=8: two chunks [0,qt] and [qt+1, 2qt+1].
// Ranks arranged so ranks {k, 8+k, 16+k} (the 3 blocks landing on one CU)
// sum to exactly 34 tiles for every k.  (round-4/6 verified)
__constant__ unsigned ATBL[24] = {
  7u|(0u<<4)|(16u<<10), 15u|(0u<<4)|(16u<<10), 14u|(0u<<4)|(15u<<10), 14u|(15u<<4)|(15u<<10),
  6u|(0u<<4)|(14u<<10), 13u|(0u<<4)|(14u<<10), 12u|(0u<<4)|(13u<<10), 11u|(0u<<4)|(12u<<10),
  15u|(16u<<4)|(16u<<10), 13u|(14u<<4)|(14u<<10), 12u|(13u<<4)|(13u<<10), 10u|(0u<<4)|(11u<<10),
  10u|(11u<<4)|(11u<<10), 9u|(0u<<4)|(10u<<10), 5u|(0u<<4)|(12u<<10), 11u|(12u<<4)|(12u<<10),
  0u|(0u<<4)|(2u<<10), 1u|(0u<<4)|(4u<<10), 2u|(0u<<4)|(6u<<10), 3u|(0u<<4)|(8u<<10),
  8u|(0u<<4)|(9u<<10), 9u|(10u<<4)|(10u<<10), 8u|(9u<<4)|(9u<<10), 4u|(0u<<4)|(10u<<10)
};

// ---------- fused pre-pass: weight transposes + input LayerNorm ----------
// blocks [0,1280): transpose+cast (bx2<64 -> w_uvqk 512x2048, else w_proj 512x512)
// blocks [1280,3328): LayerNorm over 512 + cast, 4 rows/block
__global__ void k_pre(const float* __restrict__ w1, bf16* __restrict__ o1,
                      const float* __restrict__ w2, bf16* __restrict__ o2,
                      const float* __restrict__ x, const float* __restrict__ g,
                      const float* __restrict__ bta, bf16* __restrict__ xn){
  int bx = blockIdx.x;
  int t  = threadIdx.x;
  if (bx < 1280){
    __shared__ float tile[32][33];
    int tx = t & 31, ty = t >> 5;
    int bx2 = bx % 80, by = bx / 80;
    const float* in; bf16* out; int R, C, c0;
    if (bx2 < 64){ in = w1; out = o1; R = 512; C = 2048; c0 = bx2*32; }
    else         { in = w2; out = o2; R = 512; C = 512;  c0 = (bx2-64)*32; }
    int r0 = by*32;
    #pragma unroll
    for (int i=0;i<4;i++) tile[ty+i*8][tx] = in[(size_t)(r0+ty+i*8)*C + c0+tx];
    __syncthreads();
    #pragma unroll
    for (int i=0;i<4;i++) out[(size_t)(c0+ty+i*8)*R + r0+tx] = (bf16)tile[tx][ty+i*8];
  } else {
    int lane = t & 63;
    int row  = (bx-1280)*4 + (t>>6);
    const float* xr = x + (size_t)row*512 + lane*8;
    float4 v0 = *(const float4*)xr;
    float4 v1 = *(const float4*)(xr+4);
    float vv[8] = {v0.x,v0.y,v0.z,v0.w,v1.x,v1.y,v1.z,v1.w};
    float s = 0.f, ss = 0.f;
    #pragma unroll
    for (int j=0;j<8;j++){ s += vv[j]; ss += vv[j]*vv[j]; }
    #pragma unroll
    for (int d=32; d; d>>=1){ s += __shfl_xor(s,d); ss += __shfl_xor(ss,d); }
    float m  = s * (1.f/512.f);
    float vr = ss * (1.f/512.f) - m*m;
    float rs = rsqrtf(vr + 1e-5f);
    const float* gp = g + lane*8;
    const float* bp = bta + lane*8;
    bf16x8 o;
    #pragma unroll
    for (int j=0;j<8;j++) o[j] = (bf16)((vv[j]-m)*rs*gp[j] + bp[j]);
    *(bf16x8*)(xn + (size_t)row*512 + lane*8) = o;
  }
}

// ---------- LayerNorm(attn0[+attn1]) * user gate -> bf16 ----------
__global__ void k_ln_gate(const float* __restrict__ attn0, const float* __restrict__ attn1,
                          const float* __restrict__ g, const float* __restrict__ bta,
                          const bf16* __restrict__ uvqk, bf16* __restrict__ out){
  int lane = threadIdx.x & 63;
  int row  = blockIdx.x*4 + (threadIdx.x>>6);
  const float* xr = attn0 + (size_t)row*512 + lane*8;
  float4 v0 = *(const float4*)xr;
  float4 v1 = *(const float4*)(xr+4);
  float vv[8] = {v0.x,v0.y,v0.z,v0.w,v1.x,v1.y,v1.z,v1.w};
  if (((row & (NN-1)) >> 7) >= 8){            // q-tile had 2 kv-chunks: sum partials
    const float* x2 = attn1 + (size_t)row*512 + lane*8;
    float4 w0 = *(const float4*)x2;
    float4 w1 = *(const float4*)(x2+4);
    vv[0]+=w0.x; vv[1]+=w0.y; vv[2]+=w0.z; vv[3]+=w0.w;
    vv[4]+=w1.x; vv[5]+=w1.y; vv[6]+=w1.z; vv[7]+=w1.w;
  }
  float s = 0.f, ss = 0.f;
  #pragma unroll
  for (int j=0;j<8;j++){ s += vv[j]; ss += vv[j]*vv[j]; }
  #pragma unroll
  for (int d=32; d; d>>=1){ s += __shfl_xor(s,d); ss += __shfl_xor(ss,d); }
  float m  = s * (1.f/512.f);
  float vr = ss * (1.f/512.f) - m*m;
  float rs = rsqrtf(vr + 1e-5f);
  const float* gp = g + lane*8;
  const float* bp = bta + lane*8;
  const bf16* up = uvqk + (size_t)row*NUU + (lane>>3)*256 + ((lane*8)&63);
  bf16x8 uu = *(const bf16x8*)up;
  bf16x8 o;
  #pragma unroll
  for (int j=0;j<8;j++)
    o[j] = (bf16)(((vv[j]-m)*rs*gp[j] + bp[j]) * (float)uu[j]);
  *(bf16x8*)(out + (size_t)row*512 + lane*8) = o;
}

// ---------- 128x128 bf16 MFMA GEMM, K=512, BK=64, 4 waves (2x2) ----------
// 1-D grid with XCD-chunked swizzle (gridDim.x % 8 == 0 required).
// EPI==0 additionally writes the V-slice transposed into vtout (fused k_vt):
// tiles with n0%256==0 have wc==1 covering cols [n0+64, n0+128) = V of head n0>>8.
// The V-slice is NOT stored into Cout (nothing reads it there) -> -8MB writes.
// (round-8 verified orientation; operand-swap variant regressed in round 9)
template<int EPI>
__global__ __launch_bounds__(256) void k_gemm(const bf16* __restrict__ A,
                                              const bf16* __restrict__ BT,
                                              int Nd, const float* __restrict__ resid,
                                              void* __restrict__ Cout,
                                              bf16* __restrict__ vtout){
  __shared__ __align__(16) char smem[32768];
  char* As = smem;
  char* Bs = smem + 16384;
  const int K = 512;
  int t = threadIdx.x, lane = t & 63, wid = t >> 6;
  int wr = wid >> 1, wc = wid & 1;
  int lin = blockIdx.x;
  int wk  = (lin & 7)*((int)gridDim.x >> 3) + (lin >> 3);   // XCD-chunked
  int nx  = Nd >> 7;
  int m0 = (wk / nx) * 128, n0 = (wk % nx) * 128;
  int blk = (lane & 7) ^ (lane >> 3);           // swizzled 16B-slot within row
  const bf16* gA = A  + (size_t)(m0 + wid*32 + (lane>>3))*K + blk*8;
  const bf16* gB = BT + (size_t)(n0 + wid*32 + (lane>>3))*K + blk*8;
  f32x4 acc[4][4] = {};
  for (int k0 = 0; k0 < K; k0 += 64){
    __syncthreads();
    #pragma unroll
    for (int c = 0; c < 4; ++c){
      gload16(gA + (size_t)c*8*K, As + wid*4096 + c*1024);
      gload16(gB + (size_t)c*8*K, Bs + wid*4096 + c*1024);
    }
    gA += 64; gB += 64;
    __syncthreads();
    #pragma unroll
    for (int kk = 0; kk < 64; kk += 32){
      int c0 = kk + (lane >> 4) * 8;
      bf16x8 a[4], b[4];
      #pragma unroll
      for (int i = 0; i < 4; i++){
        int ra = wr*64 + i*16 + (lane & 15);
        a[i] = *(const bf16x8*)(As + (((ra*64 + c0)*2) ^ ((ra & 7) << 4)));
        int rb = wc*64 + i*16 + (lane & 15);
        b[i] = *(const bf16x8*)(Bs + (((rb*64 + c0)*2) ^ ((rb & 7) << 4)));
      }
      #pragma unroll
      for (int i = 0; i < 4; i++)
        #pragma unroll
        for (int jj = 0; jj < 4; jj++)
          acc[i][jj] = __builtin_amdgcn_mfma_f32_16x16x32_bf16(a[i], b[jj], acc[i][jj], 0, 0, 0);
    }
  }
  bool isv = (EPI == 0) && ((n0 & 255) == 0) && (wc == 1);
  #pragma unroll
  for (int i = 0; i < 4; i++){
    #pragma unroll
    for (int jj = 0; jj < 4; jj++){
      int col = n0 + wc*64 + jj*16 + (lane & 15);
      if (EPI == 0){
        union { unsigned long long u; ushort s[4]; } pw;
        #pragma unroll
        for (int r = 0; r < 4; r++){
          int rowg = m0 + wr*64 + i*16 + (lane >> 4)*4 + r;
          float sv = silu_fast(acc[i][jj][r]);
          if (!isv) ((bf16*)Cout)[(size_t)rowg*Nd + col] = (bf16)sv;
          pw.s[r] = __builtin_bit_cast(ushort, (bf16)sv);
        }
        if (isv){
          int dh    = jj*16 + (lane & 15);
          int rowg0 = m0 + wr*64 + i*16 + (lane >> 4)*4;
          int bb = rowg0 >> 11, nn = rowg0 & (NN-1);
          int hh = n0 >> 8;
          *(unsigned long long*)(vtout + ((size_t)((bb*HH + hh)*64 + dh)*NN + nn)) = pw.u;
        }
      } else {
        #pragma unroll
        for (int r = 0; r < 4; r++){
          int rowg = m0 + wr*64 + i*16 + (lane >> 4)*4 + r;
          ((float*)Cout)[(size_t)rowg*Nd + col] = acc[i][jj][r] + resid[(size_t)rowg*Nd + col];
        }
      }
    }
  }
}

// ---------- HSTU attention: best verified (rounds 8-10, ~40.0us) ----------
// QBLK=128, 4 waves x 32 q-rows, 32x32x16 MFMA, K/V double-buffered in LDS
// (32KB), P in registers via permlane32_swap, <=2 kv-chunks per q-tile with
// plain stores into attn0/attn1 (no atomics, no memset), ATBL-balanced
// 768 blocks = 3/CU, single barrier per kv-tile, T5 setprio around MFMA.
__global__ __launch_bounds__(256, 4) void k_attn(const bf16* __restrict__ uv,
                                                 const bf16* __restrict__ vt,
                                                 float* __restrict__ attn0,
                                                 float* __restrict__ attn1,
                                                 const int* __restrict__ scal){
  __shared__ __align__(16) char smem[32768];
  // buf c (c=0,1): K[64][64] at smem+c*16384, V^T[64][64] at +8192
  int t = threadIdx.x, lane = t & 63, w = t >> 6;     // w = 0..3
  int hi5 = lane >> 5;
  int l31 = lane & 31;
  int lin = blockIdx.x;                       // 0..767 hardware dispatch order
  int pos = lin & 255;                        // ~CU slot (XCD round-robin)
  int grp = pos & 31;                         // (b,h): 4 groups per XCD per slot
  int rank = (lin >> 8)*8 + (pos >> 5);       // 0..23
  unsigned e = ATBL[rank];
  int qt = e & 15;
  int j0 = (int)((e >> 4) & 63);
  int j1 = j0 + (int)(e >> 10) - 1;
  float* ob = j0 ? attn1 : attn0;             // j0>0 <=> second chunk of a pair
  int b = grp >> 3, h = grp & 7;
  int tok0 = b*NN + qt*128;
  float sinv = 1.0f / (float)(scal[0]);       // = 2^-11 exact; applied at epilogue

  int blk  = (lane & 7) ^ (lane >> 3);      // pre-swizzled 16B slot within 128B row
  int rsub = lane >> 3;                     // row-within-8

  // ---- Q fragments straight from global (32B row segments, L2/L3-resident) ----
  bf16x8 qfrag[4];
  {
    const bf16* gq = uv + (size_t)(tok0 + w*32 + l31)*NUU + h*256 + 128 + hi5*8;
    #pragma unroll
    for (int ks = 0; ks < 4; ++ks)
      qfrag[ks] = *(const bf16x8*)(gq + ks*16);
  }
  // ---- prologue: stage K/V(j0) into buf0 (4 DMA loads per wave) ----
  const bf16* gk = uv + (size_t)(b*NN + j0*64 + w*16 + rsub)*NUU + h*256 + 192 + blk*8;
  const bf16* gv = vt + (size_t)((b*HH + h)*64 + w*16 + rsub)*NN + j0*64 + blk*8;
  gload16(gk,                  smem + w*2048);
  gload16(gk + (size_t)8*NUU,  smem + w*2048 + 1024);
  gload16(gv,                  smem + 8192 + w*2048);
  gload16(gv + (size_t)8*NN,   smem + 8192 + w*2048 + 1024);
  gk += (size_t)64*NUU; gv += 64;

  f32x16 oacc[2] = {};
  int qmin  = qt*128 + w*32;                 // this wave's lowest q row (global)
  int qglob = qmin + l31;                    // lane's q row (global)
  int cur = 0;
  for (int j = j0; j <= j1; ++j){
    // wait for buf[cur]'s staging (issued last iteration; had the whole
    // previous compute phase to land), then the single barrier: buf[cur]
    // complete for all waves AND all waves done reading buf[cur^1]
    asm volatile("s_waitcnt vmcnt(0)" ::: "memory");
    __builtin_amdgcn_s_barrier();
    if (j < j1){                             // prefetch(j+1) into the free buffer
      char* nb = smem + (cur^1)*16384;
      gload16(gk,                 nb + w*2048);
      gload16(gk + (size_t)8*NUU, nb + w*2048 + 1024);
      gload16(gv,                 nb + 8192 + w*2048);
      gload16(gv + (size_t)8*NN,  nb + 8192 + w*2048 + 1024);
      gk += (size_t)64*NUU; gv += 64;
    }
    const char* Ks = smem + cur*16384;
    const char* Vs = Ks + 8192;
    #pragma unroll
    for (int sub = 0; sub < 2; ++sub){
      int kvbase = j*64 + sub*32;
      if (kvbase < qmin + 32){               // wave-uniform: not fully masked
        // S^T = K @ Q^T : A = K rows (kv), B = Q rows (q)
        f32x16 sacc = {};
        int rk = sub*32 + l31;
        __builtin_amdgcn_s_setprio(1);
        #pragma unroll
        for (int ks = 0; ks < 4; ++ks){
          int c0 = ks*16 + hi5*8;
          bf16x8 ak = *(const bf16x8*)(Ks + (((rk*64 + c0)*2) ^ ((rk & 7) << 4)));
          sacc = __builtin_amdgcn_mfma_f32_32x32x16_bf16(ak, qfrag[ks], sacc, 0, 0, 0);
        }
        __builtin_amdgcn_s_setprio(0);
        // sacc reg r = S[kv = kvbase + (r&3)+4*hi5+8*(r>>2)][q = qglob]
        union { unsigned u[8]; bf16x8 v[2]; } P;
        if (kvbase + 31 <= qmin){
          // fully causal for this wave: no per-element mask
          #pragma unroll
          for (int m = 0; m < 4; ++m){
            P.u[2*m]   = pk2(silu_fast(sacc[4*m+0]), silu_fast(sacc[4*m+1]));
            P.u[2*m+1] = pk2(silu_fast(sacc[4*m+2]), silu_fast(sacc[4*m+3]));
          }
        } else {
          #pragma unroll
          for (int m = 0; m < 4; ++m){
            float pr[4];
            #pragma unroll
            for (int r = 0; r < 4; ++r){
              int kvg = kvbase + 8*m + 4*hi5 + r;
              pr[r] = (kvg <= qglob) ? silu_fast(sacc[4*m+r]) : 0.0f;
            }
            P.u[2*m]   = pk2(pr[0], pr[1]);
            P.u[2*m+1] = pk2(pr[2], pr[3]);
          }
        }
        // in-register redistribution to PV A-fragment layout
        plswap(P.u[0], P.u[2]); plswap(P.u[1], P.u[3]);
        plswap(P.u[4], P.u[6]); plswap(P.u[5], P.u[7]);
        // PV: A = P rows (q), B = V^T rows (dh)
        __builtin_amdgcn_s_setprio(1);
        #pragma unroll
        for (int kh = 0; kh < 2; ++kh){
          int c0 = sub*32 + kh*16 + hi5*8;
          #pragma unroll
          for (int dsb = 0; dsb < 2; ++dsb){
            int rv = dsb*32 + l31;
            bf16x8 vb = *(const bf16x8*)(Vs + (((rv*64 + c0)*2) ^ ((rv & 7) << 4)));
            oacc[dsb] = __builtin_amdgcn_mfma_f32_32x32x16_bf16(P.v[kh], vb, oacc[dsb], 0, 0, 0);
          }
        }
        __builtin_amdgcn_s_setprio(0);
      }
    }
    cur ^= 1;
  }
  // oacc[dsb] reg r = O[q = (r&3)+4*hi5+8*(r>>2)][dh = dsb*32 + l31]
  // plain coalesced stores into this chunk's partial buffer
  #pragma unroll
  for (int dsb = 0; dsb < 2; ++dsb){
    #pragma unroll
    for (int r = 0; r < 16; ++r){
      int qrow = (r & 3) + 4*hi5 + 8*(r >> 2);
      ob[(size_t)(tok0 + w*32 + qrow)*DD + h*64 + dsb*32 + l31] = oacc[dsb][r] * sinv;
    }
  }
}

extern "C" void kernel_launch(void* const* d_in, const int* in_sizes, int n_in,
                              void* d_out, int out_size, void* d_ws, size_t ws_size,
                              hipStream_t stream){
  (void)in_sizes; (void)n_in; (void)out_size; (void)ws_size;
  const float* x      = (const float*)d_in[0];
  const float* ln1_g  = (const float*)d_in[1];
  const float* ln1_b  = (const float*)d_in[2];
  const float* w_uvqk = (const float*)d_in[3];
  const float* ln2_g  = (const float*)d_in[4];
  const float* ln2_b  = (const float*)d_in[5];
  const float* w_proj = (const float*)d_in[6];
  const int*   scal   = (const int*)d_in[7];
  float* out = (float*)d_out;

  char* ws = (char*)d_ws;
  bf16*  wT1  = (bf16*)(ws);                          // 2 MB   [2048][512]
  bf16*  wT2  = (bf16*)(ws + (2u<<20));               // 0.5 MB [512][512]
  bf16*  xn   = (bf16*)(ws + (2u<<20) + (512u<<10));  // 8 MB   [8192][512] (reused as gated)
  bf16*  uvq  = (bf16*)(ws + (10u<<20) + (512u<<10)); // 32 MB  [8192][2048]
  float* attn0= (float*)(ws + (42u<<20) + (512u<<10));// 16 MB  [8192][512] f32 (chunk 0)
  bf16*  vtb  = (bf16*)(ws + (58u<<20) + (512u<<10)); // 8 MB   [4][8][64][2048]
  float* attn1= (float*)(ws + (66u<<20) + (512u<<10));// 16 MB  [8192][512] f32 (chunk 1)

  k_pre<<<dim3(3328), dim3(256), 0, stream>>>(w_uvqk, wT1, w_proj, wT2,
                                              x, ln1_g, ln1_b, xn);
  k_gemm<0><<<dim3(1024), dim3(256), 0, stream>>>(xn, wT1, 2048, nullptr, (void*)uvq, vtb);
  k_attn<<<dim3(768), dim3(256), 0, stream>>>(uvq, vtb, attn0, attn1, scal);
  k_ln_gate<<<TT/4, 256, 0, stream>>>(attn0, attn1, ln2_g, ln2_b, uvq, xn);
  k_gemm<1><<<dim3(256), dim3(256), 0, stream>>>(xn, wT2, 512, x, (void*)out, nullptr);
}